// Round 12
// baseline (35.853 us; speedup 1.0000x reference)
//
#include <hip/hip_runtime.h>

// Problem constants (from reference)
constexpr int Bn = 8, Hn = 1536, Wn = 2048;
constexpr int NUM_GTS = 64;
constexpr int PLANE   = Hn * Wn;            // 3145728 elements per batch plane
constexpr int BLOCKS  = 1024;               // 4 blocks/CU, fully resident
constexpr int GSTRIDE = BLOCKS * 256;       // 262144 threads; 3 groups per thread
constexpr float INV_N = 1.0f / (float)((long long)Bn * PLANE);

typedef float v2f __attribute__((ext_vector_type(2)));

// CDNA packed f32: one issue slot per 2 elements.
__device__ __forceinline__ v2f pk_fma(v2f a, v2f b, v2f c) {
    v2f d;
    asm("v_pk_fma_f32 %0, %1, %2, %3" : "=v"(d) : "v"(a), "v"(b), "v"(c));
    return d;
}
__device__ __forceinline__ v2f pk_add(v2f a, v2f b) {
    v2f d;
    asm("v_pk_add_f32 %0, %1, %2" : "=v"(d) : "v"(a), "v"(b));
    return d;
}

// Degree-8 Taylor poly of g(x)=softplus(x)*sigmoid(x)^2 on [-1,1].
// Max abs err 1.3e-4 (threshold 4.7e-3 -> 30x slack worst-case).
__device__ __forceinline__ v2f g_poly2(v2f x) {
    const float c0 = 0.173286795f, c1 = 0.298286795f, c2 = 0.199571699f,
                c3 = 0.048059430f, c4 = -0.011126533f, c5 = -0.007670527f,
                c6 = 0.000523747f, c7 = 0.001047450f, c8 = 0.000015192f;
    v2f t = (v2f){c8, c8};
    t = pk_fma(t, x, (v2f){c7, c7});
    t = pk_fma(t, x, (v2f){c6, c6});
    t = pk_fma(t, x, (v2f){c5, c5});
    t = pk_fma(t, x, (v2f){c4, c4});
    t = pk_fma(t, x, (v2f){c3, c3});
    t = pk_fma(t, x, (v2f){c2, c2});
    t = pk_fma(t, x, (v2f){c1, c1});
    t = pk_fma(t, x, (v2f){c0, c0});
    return t;
}

// DPP wave-64 sum (VALU-speed, ~8 cyc/stage vs ~60 cyc/stage for shfl's
// LDS-pipe bpermute). row_shr 1/2/4/8 builds row(16) prefix sums with
// bound_ctrl=0-fill; row_bcast:15 (rows 1,3) then row_bcast:31 (rows 2,3)
// fold rows. Total lands in lane 63. Canonical GCN sequence.
template <int CTRL, int RM>
__device__ __forceinline__ float dpp_add(float x) {
    const int t = __builtin_amdgcn_update_dpp(0, __float_as_int(x),
                                              CTRL, RM, 0xF, true);
    return x + __int_as_float(t);
}
__device__ __forceinline__ float wave_sum63(float x) {
    x = dpp_add<0x111, 0xF>(x);   // row_shr:1
    x = dpp_add<0x112, 0xF>(x);   // row_shr:2
    x = dpp_add<0x114, 0xF>(x);   // row_shr:4
    x = dpp_add<0x118, 0xF>(x);   // row_shr:8
    x = dpp_add<0x142, 0xA>(x);   // row_bcast:15 -> rows 1,3
    x = dpp_add<0x143, 0xC>(x);   // row_bcast:31 -> rows 2,3
    return x;                     // lane 63 = wave total
}

// Column-mask for one pixel-group. Wave lies in a single row, so lane i tests
// box i's row interval and one ballot gives the per-row active-box mask.
__device__ __forceinline__ unsigned group_tbits(int r, int c0, int tly, int bry,
                                                const int* s_tlx, const int* s_brx) {
    const bool rowhit = (r >= tly - 1) && (r < bry);
    unsigned long long rowm = __ballot(rowhit);
    unsigned tb = 0u;
    while (rowm) {
        const int i = __ffsll((unsigned long long)rowm) - 1;
        rowm &= rowm - 1;
        int lo = s_tlx[i] - 1 - c0;
        int hi = s_brx[i] - c0;
        lo = lo < 0 ? 0 : lo;
        hi = hi > 4 ? 4 : hi;
        if (lo < hi) tb |= ((1u << hi) - (1u << lo));
    }
    return tb;
}

// Fused single-dispatch kernel. Main body = round-11 champion (plane-
// sequential sweep). Tail = last-block-done reduction with ZERO cache-
// maintenance ops:
//   - partials: RELAXED agent-scope atomic stores (write-through past the
//     non-coherent per-XCD L2; no wbl2 fence -- round 9's 5x regression was
//     the per-block RELEASE/ACQ_REL fences, each an L2 writeback/invalidate)
//   - s_waitcnt vmcnt(0) orders partial-store completion before the counter
//   - counter: RELAXED agent-scope fetch_add; cnt memset to 0 each call so
//     old==1023 is the TRUE last arrival (round-8 bug fixed)
//   - reducer: RELAXED agent-scope atomic loads (L2-bypassing), fixed
//     summation order -> bitwise deterministic.
__global__ __launch_bounds__(256) void depth_loss_kernel(
    const float* __restrict__ depth,
    const int*   __restrict__ bbox,
    float*       __restrict__ ws,
    unsigned*    __restrict__ cnt,
    float*       __restrict__ out)
{
    __shared__ int s_tlx[NUM_GTS], s_brx[NUM_GTS];
    const int tid = threadIdx.x;
    if (tid < NUM_GTS) {
        s_tlx[tid] = bbox[tid * 4 + 0];
        s_brx[tid] = bbox[tid * 4 + 2];
    }
    __syncthreads();

    const int lane = tid & 63;
    const int tly  = bbox[lane * 4 + 1];    // per-lane own box, for the ballot
    const int bry  = bbox[lane * 4 + 3];

    const int g0 = blockIdx.x * 256 + tid;
    const int g1 = g0 + GSTRIDE;
    const int g2 = g1 + GSTRIDE;

    // Per-group element bases (gid*4 = r*Wn + c0 exactly).
    const float* p0 = depth + (g0 << 2);
    const float* p1 = depth + (g1 << 2);
    const float* p2 = depth + (g2 << 2);

    // Per-group sign constants, computed once (masks are plane-independent).
    const unsigned tbs[3] = {
        group_tbits(g0 >> 9, (g0 & 511) << 2, tly, bry, s_tlx, s_brx),
        group_tbits(g1 >> 9, (g1 & 511) << 2, tly, bry, s_tlx, s_brx),
        group_tbits(g2 >> 9, (g2 & 511) << 2, tly, bry, s_tlx, s_brx)};
    v2f s01[3], s23[3], n01[3], n23[3];
#pragma unroll
    for (int j = 0; j < 3; ++j) {
        const float sg0 = (tbs[j] & 1u) ? -1.0f : 1.0f;
        const float sg1 = (tbs[j] & 2u) ? -1.0f : 1.0f;
        const float sg2 = (tbs[j] & 4u) ? -1.0f : 1.0f;
        const float sg3 = (tbs[j] & 8u) ? -1.0f : 1.0f;
        s01[j] = (v2f){sg0, sg1};
        s23[j] = (v2f){sg2, sg3};
        n01[j] = (v2f){-2.0f * sg0, -2.0f * sg1};
        n23[j] = (v2f){-2.0f * sg2, -2.0f * sg3};
    }

#define LOAD3(dst, b)                                                          \
    do {                                                                       \
        dst[0] = *reinterpret_cast<const float4*>(p0 + (b) * PLANE);           \
        dst[1] = *reinterpret_cast<const float4*>(p1 + (b) * PLANE);           \
        dst[2] = *reinterpret_cast<const float4*>(p2 + (b) * PLANE);           \
    } while (0)

    float4 cur[3], nxt[3];
    LOAD3(cur, 0);

    v2f acc2 = (v2f){0.0f, 0.0f};
#pragma unroll
    for (int b = 0; b < Bn; ++b) {
        if (b + 1 < Bn) LOAD3(nxt, b + 1);      // prefetch next plane
#pragma unroll
        for (int j = 0; j < 3; ++j) {
            const v2f q01 = (v2f){cur[j].x, cur[j].y};
            const v2f q23 = (v2f){cur[j].z, cur[j].w};
            acc2 = pk_add(acc2, g_poly2(pk_fma(n01[j], q01, s01[j])));
            acc2 = pk_add(acc2, g_poly2(pk_fma(n23[j], q23, s23[j])));
        }
#pragma unroll
        for (int j = 0; j < 3; ++j) cur[j] = nxt[j];
    }

    // DPP wave reduce (lane 63 holds wave total), LDS block combine.
    float acc = wave_sum63(acc2.x + acc2.y);

    __shared__ float s_part[4];
    __shared__ int   s_last;
    if (lane == 63) s_part[tid >> 6] = acc;
    __syncthreads();

    if (tid == 0) {
        const float part = s_part[0] + s_part[1] + s_part[2] + s_part[3];
        __hip_atomic_store(&ws[blockIdx.x], part,
                           __ATOMIC_RELAXED, __HIP_MEMORY_SCOPE_AGENT);
        asm volatile("s_waitcnt vmcnt(0)" ::: "memory");  // partial at L3 first
        const unsigned old = __hip_atomic_fetch_add(cnt, 1u,
                           __ATOMIC_RELAXED, __HIP_MEMORY_SCOPE_AGENT);
        s_last = (old == (unsigned)(BLOCKS - 1));         // true last arrival
    }
    __syncthreads();

    if (s_last) {
        float s = 0.0f;
#pragma unroll
        for (int k = 0; k < 4; ++k)
            s += __hip_atomic_load(&ws[tid + k * 256],
                                   __ATOMIC_RELAXED, __HIP_MEMORY_SCOPE_AGENT);
        s = wave_sum63(s);
        if (lane == 63) s_part[tid >> 6] = s;
        __syncthreads();
        if (tid == 0)
            out[0] = (s_part[0] + s_part[1] + s_part[2] + s_part[3]) * INV_N;
    }
}

extern "C" void kernel_launch(void* const* d_in, const int* in_sizes, int n_in,
                              void* d_out, int out_size, void* d_ws, size_t ws_size,
                              hipStream_t stream) {
    const float* depth = (const float*)d_in[0];
    const int*   bbox  = (const int*)d_in[1];
    float*       out   = (float*)d_out;
    float*       ws    = (float*)d_ws;
    unsigned*    cnt   = (unsigned*)((char*)d_ws + BLOCKS * sizeof(float));

    hipMemsetAsync(cnt, 0, sizeof(unsigned), stream);   // counter = 0 each call
    depth_loss_kernel<<<BLOCKS, 256, 0, stream>>>(depth, bbox, ws, cnt, out);
}

// Round 13
// 24.005 us; speedup vs baseline: 1.4936x; 1.4936x over previous
//
#include <hip/hip_runtime.h>

// Problem constants (from reference)
constexpr int Bn = 8, Hn = 1536, Wn = 2048;
constexpr int NUM_GTS = 64;
constexpr int PLANE   = Hn * Wn;            // 3145728 elements per batch plane
constexpr int BLOCKS  = 1024;               // 4 blocks/CU, fully resident
constexpr int GSTRIDE = BLOCKS * 256;       // 262144 threads; 3 groups per thread
constexpr float INV_N = 1.0f / (float)((long long)Bn * PLANE);

typedef float v2f __attribute__((ext_vector_type(2)));

// CDNA packed f32: one issue slot per 2 elements.
__device__ __forceinline__ v2f pk_fma(v2f a, v2f b, v2f c) {
    v2f d;
    asm("v_pk_fma_f32 %0, %1, %2, %3" : "=v"(d) : "v"(a), "v"(b), "v"(c));
    return d;
}
__device__ __forceinline__ v2f pk_add(v2f a, v2f b) {
    v2f d;
    asm("v_pk_add_f32 %0, %1, %2" : "=v"(d) : "v"(a), "v"(b));
    return d;
}

// Degree-8 Taylor poly of g(x)=softplus(x)*sigmoid(x)^2 on [-1,1].
// Max abs err 1.3e-4 (threshold 4.7e-3 -> 30x slack worst-case).
__device__ __forceinline__ v2f g_poly2(v2f x) {
    const float c0 = 0.173286795f, c1 = 0.298286795f, c2 = 0.199571699f,
                c3 = 0.048059430f, c4 = -0.011126533f, c5 = -0.007670527f,
                c6 = 0.000523747f, c7 = 0.001047450f, c8 = 0.000015192f;
    v2f t = (v2f){c8, c8};
    t = pk_fma(t, x, (v2f){c7, c7});
    t = pk_fma(t, x, (v2f){c6, c6});
    t = pk_fma(t, x, (v2f){c5, c5});
    t = pk_fma(t, x, (v2f){c4, c4});
    t = pk_fma(t, x, (v2f){c3, c3});
    t = pk_fma(t, x, (v2f){c2, c2});
    t = pk_fma(t, x, (v2f){c1, c1});
    t = pk_fma(t, x, (v2f){c0, c0});
    return t;
}

// DPP wave-64 sum (VALU-speed; verified bit-exact in round 12).
// row_shr 1/2/4/8 build within-row(16) sums (bound_ctrl=0-fill);
// row_bcast:15 then row_bcast:31 fold rows. Lane 63 holds the total.
template <int CTRL, int RM>
__device__ __forceinline__ float dpp_add(float x) {
    const int t = __builtin_amdgcn_update_dpp(0, __float_as_int(x),
                                              CTRL, RM, 0xF, true);
    return x + __int_as_float(t);
}
__device__ __forceinline__ float wave_sum63(float x) {
    x = dpp_add<0x111, 0xF>(x);   // row_shr:1
    x = dpp_add<0x112, 0xF>(x);   // row_shr:2
    x = dpp_add<0x114, 0xF>(x);   // row_shr:4
    x = dpp_add<0x118, 0xF>(x);   // row_shr:8
    x = dpp_add<0x142, 0xA>(x);   // row_bcast:15 -> rows 1,3
    x = dpp_add<0x143, 0xC>(x);   // row_bcast:31 -> rows 2,3
    return x;                     // lane 63 = wave total
}

// Column-mask for one pixel-group. Wave lies in a single row, so lane i tests
// box i's row interval and one ballot gives the per-row active-box mask.
__device__ __forceinline__ unsigned group_tbits(int r, int c0, int tly, int bry,
                                                const int* s_tlx, const int* s_brx) {
    const bool rowhit = (r >= tly - 1) && (r < bry);
    unsigned long long rowm = __ballot(rowhit);
    unsigned tb = 0u;
    while (rowm) {
        const int i = __ffsll((unsigned long long)rowm) - 1;
        rowm &= rowm - 1;
        int lo = s_tlx[i] - 1 - c0;
        int hi = s_brx[i] - c0;
        lo = lo < 0 ? 0 : lo;
        hi = hi > 4 ? 4 : hi;
        if (lo < hi) tb |= ((1u << hi) - (1u << lo));
    }
    return tb;
}

// Round-11 champion body: plane-sequential sweep, double-buffered prefetch,
// packed-f32 polynomial, per-block partial to ws, separate 1-wave reducer.
// (Fused single-dispatch tails are dead on this harness: counter reset needs
// hipMemsetAsync, and ANY memset in kernel_launch costs ~8-11 us in the
// captured graph -- r1/r2/r4/r12 all show it; r8 shows un-reset counters
// mis-fire; r9 shows fence-based coherence costs 5x.)
__global__ __launch_bounds__(256) void depth_loss_kernel(
    const float* __restrict__ depth,
    const int*   __restrict__ bbox,
    float*       __restrict__ ws)
{
    __shared__ int s_tlx[NUM_GTS], s_brx[NUM_GTS];
    const int tid = threadIdx.x;
    if (tid < NUM_GTS) {
        s_tlx[tid] = bbox[tid * 4 + 0];
        s_brx[tid] = bbox[tid * 4 + 2];
    }
    __syncthreads();

    const int lane = tid & 63;
    const int tly  = bbox[lane * 4 + 1];    // per-lane own box, for the ballot
    const int bry  = bbox[lane * 4 + 3];

    const int g0 = blockIdx.x * 256 + tid;
    const int g1 = g0 + GSTRIDE;
    const int g2 = g1 + GSTRIDE;

    // Per-group element bases (gid*4 = r*Wn + c0 exactly).
    const float* p0 = depth + (g0 << 2);
    const float* p1 = depth + (g1 << 2);
    const float* p2 = depth + (g2 << 2);

    // Per-group sign constants, computed once (masks are plane-independent).
    const unsigned tbs[3] = {
        group_tbits(g0 >> 9, (g0 & 511) << 2, tly, bry, s_tlx, s_brx),
        group_tbits(g1 >> 9, (g1 & 511) << 2, tly, bry, s_tlx, s_brx),
        group_tbits(g2 >> 9, (g2 & 511) << 2, tly, bry, s_tlx, s_brx)};
    v2f s01[3], s23[3], n01[3], n23[3];
#pragma unroll
    for (int j = 0; j < 3; ++j) {
        const float sg0 = (tbs[j] & 1u) ? -1.0f : 1.0f;
        const float sg1 = (tbs[j] & 2u) ? -1.0f : 1.0f;
        const float sg2 = (tbs[j] & 4u) ? -1.0f : 1.0f;
        const float sg3 = (tbs[j] & 8u) ? -1.0f : 1.0f;
        s01[j] = (v2f){sg0, sg1};
        s23[j] = (v2f){sg2, sg3};
        n01[j] = (v2f){-2.0f * sg0, -2.0f * sg1};
        n23[j] = (v2f){-2.0f * sg2, -2.0f * sg3};
    }

#define LOAD3(dst, b)                                                          \
    do {                                                                       \
        dst[0] = *reinterpret_cast<const float4*>(p0 + (b) * PLANE);           \
        dst[1] = *reinterpret_cast<const float4*>(p1 + (b) * PLANE);           \
        dst[2] = *reinterpret_cast<const float4*>(p2 + (b) * PLANE);           \
    } while (0)

    float4 cur[3], nxt[3];
    LOAD3(cur, 0);

    v2f acc2 = (v2f){0.0f, 0.0f};
#pragma unroll
    for (int b = 0; b < Bn; ++b) {
        if (b + 1 < Bn) LOAD3(nxt, b + 1);      // prefetch next plane
#pragma unroll
        for (int j = 0; j < 3; ++j) {
            const v2f q01 = (v2f){cur[j].x, cur[j].y};
            const v2f q23 = (v2f){cur[j].z, cur[j].w};
            acc2 = pk_add(acc2, g_poly2(pk_fma(n01[j], q01, s01[j])));
            acc2 = pk_add(acc2, g_poly2(pk_fma(n23[j], q23, s23[j])));
        }
#pragma unroll
        for (int j = 0; j < 3; ++j) cur[j] = nxt[j];
    }

    // DPP wave reduce (lane 63 holds wave total), LDS block combine.
    float acc = wave_sum63(acc2.x + acc2.y);

    __shared__ float s_part[4];
    if (lane == 63) s_part[tid >> 6] = acc;
    __syncthreads();
    if (tid == 0)
        ws[blockIdx.x] = s_part[0] + s_part[1] + s_part[2] + s_part[3];
}

// Single-wave reduce of 1024 partials: 16 independent loads in flight, no LDS.
__global__ __launch_bounds__(64) void reduce_kernel(
    const float* __restrict__ ws,
    float*       __restrict__ out)
{
    const int tid = threadIdx.x;
    float s = 0.0f;
#pragma unroll
    for (int i = 0; i < 16; ++i)
        s += ws[tid + i * 64];
    s = wave_sum63(s);
    if (tid == 63)
        out[0] = s * INV_N;
}

extern "C" void kernel_launch(void* const* d_in, const int* in_sizes, int n_in,
                              void* d_out, int out_size, void* d_ws, size_t ws_size,
                              hipStream_t stream) {
    const float* depth = (const float*)d_in[0];
    const int*   bbox  = (const int*)d_in[1];
    float*       out   = (float*)d_out;
    float*       ws    = (float*)d_ws;

    depth_loss_kernel<<<BLOCKS, 256, 0, stream>>>(depth, bbox, ws);
    reduce_kernel<<<1, 64, 0, stream>>>(ws, out);
}